// Round 3
// baseline (481.587 us; speedup 1.0000x reference)
//
#include <hip/hip_runtime.h>

typedef unsigned short u16;
typedef __attribute__((ext_vector_type(8))) short bf16x8;
typedef __attribute__((ext_vector_type(4))) float f32x4;

// ---- constants: B=8 N=4096 C=768 H=8 D=96, M = B*N = 32768 ----
#define M_TOT 32768

__device__ __forceinline__ u16 f2b(float x) {
    union { float f; unsigned u; } c; c.f = x;
    unsigned r = c.u + 0x7fffu + ((c.u >> 16) & 1u);  // RNE
    return (u16)(r >> 16);
}

__device__ __forceinline__ bf16x8 cvt8(f32x4 a, f32x4 b) {
    union { bf16x8 v; u16 s[8]; } r;
    r.s[0] = f2b(a.x); r.s[1] = f2b(a.y); r.s[2] = f2b(a.z); r.s[3] = f2b(a.w);
    r.s[4] = f2b(b.x); r.s[5] = f2b(b.y); r.s[6] = f2b(b.z); r.s[7] = f2b(b.w);
    return r.v;
}

// ============================================================
// prep_b1: B1[d,k] (96 x 1536 bf16), k<768 -> w1 * sum_h W_qkv_rgb[1536+h*96+d, k]
//                                    k>=768 -> w0 * sum_h W_qkv_depth[768+h*96+d, k-768]
// fb[d] = w1 * sum_h b_qkv_rgb[1536+h*96+d] + w0 * sum_h b_qkv_depth[768+h*96+d]
// ============================================================
__global__ void prep_b1(const float* __restrict__ Wr, const float* __restrict__ Wd,
                        const float* __restrict__ br, const float* __restrict__ bd,
                        const float* __restrict__ aw,
                        u16* __restrict__ B1, float* __restrict__ fb) {
    int id = blockIdx.x * 256 + threadIdx.x;
    if (id >= 96 * 1536) return;
    int d = id / 1536, k = id - d * 1536;
    float w0 = 1.f / (1.f + __expf(-aw[0]));
    float w1 = 1.f / (1.f + __expf(-aw[1]));
    float s = 0.f, v;
    if (k < 768) {
        for (int h = 0; h < 8; h++) s += Wr[(size_t)(1536 + h * 96 + d) * 768 + k];
        v = w1 * s;
    } else {
        for (int h = 0; h < 8; h++) s += Wd[(size_t)(768 + h * 96 + d) * 768 + (k - 768)];
        v = w0 * s;
    }
    B1[id] = f2b(v);
    if (k == 0) {
        float t = 0.f;
        for (int h = 0; h < 8; h++)
            t += w1 * br[1536 + h * 96 + d] + w0 * bd[768 + h * 96 + d];
        fb[d] = t;
    }
}

// ============================================================
// prep_weff: Weff[c,d] (768 x 96 bf16) = sum_h W_out[c, h*96+d]
// ============================================================
__global__ void prep_weff(const float* __restrict__ Wo, u16* __restrict__ Weff) {
    int id = blockIdx.x * 256 + threadIdx.x;
    if (id >= 768 * 96) return;
    int c = id / 96, d = id - c * 96;
    float s = 0.f;
    for (int h = 0; h < 8; h++) s += Wo[(size_t)c * 768 + h * 96 + d];
    Weff[id] = f2b(s);
}

// ============================================================
// gemm_f: f(32768 x 96) = [Xr | Xd](32768 x 1536) @ B1^T + fb, stored bf16.
// NO LDS, NO BARRIERS: each wave owns a 16-row strip; A-fragments are loaded
// directly from global (lane = row fr, k-octet fk) as 2 adjacent f32x4 and
// converted in-register; B-fragments come straight from L2 (B1 = 294 KB hot).
// out0 = x_rgb passthrough fused into the rgb-half A loads (each element
// loaded exactly once). Grid 512 x 256 (4 waves/block, strip = blk*64+wave*16).
// ============================================================
__global__ __launch_bounds__(256) void gemm_f(const float* __restrict__ Xr,
                                              const float* __restrict__ Xd,
                                              const u16* __restrict__ B1,
                                              const float* __restrict__ fb,
                                              float* __restrict__ out0,
                                              u16* __restrict__ fbuf) {
    const int tid = threadIdx.x;
    const int lane = tid & 63, wave = tid >> 6;
    const int fr = lane & 15, fk = (lane >> 4) * 8;
    const int mrow = blockIdx.x * 64 + wave * 16;      // strip base
    const int m = mrow + fr;                           // this lane's A row
    const float* __restrict__ xr_row = Xr + (size_t)m * 768;
    const float* __restrict__ xd_row = Xd + (size_t)m * 768;
    float* __restrict__ o0_row = out0 + (size_t)m * 768;

    f32x4 acc[6] = {};

    // ---- rgb half: k 0..767, with fused out0 copy ----
#pragma unroll 2
    for (int ks = 0; ks < 12; ks++) {
#pragma unroll
        for (int s = 0; s < 2; s++) {
            const int kc = ks * 64 + s * 32 + fk;
            f32x4 v0 = *(const f32x4*)&xr_row[kc];
            f32x4 v1 = *(const f32x4*)&xr_row[kc + 4];
            __builtin_nontemporal_store(v0, (f32x4*)&o0_row[kc]);
            __builtin_nontemporal_store(v1, (f32x4*)&o0_row[kc + 4]);
            bf16x8 a = cvt8(v0, v1);
#pragma unroll
            for (int j = 0; j < 6; j++) {
                bf16x8 b = *(const bf16x8*)&B1[(size_t)(j * 16 + fr) * 1536 + kc];
                acc[j] = __builtin_amdgcn_mfma_f32_16x16x32_bf16(a, b, acc[j], 0, 0, 0);
            }
        }
    }
    // ---- depth half: k 768..1535 ----
#pragma unroll 2
    for (int ks = 0; ks < 12; ks++) {
#pragma unroll
        for (int s = 0; s < 2; s++) {
            const int kc = ks * 64 + s * 32 + fk;
            f32x4 v0 = *(const f32x4*)&xd_row[kc];
            f32x4 v1 = *(const f32x4*)&xd_row[kc + 4];
            bf16x8 a = cvt8(v0, v1);
#pragma unroll
            for (int j = 0; j < 6; j++) {
                bf16x8 b = *(const bf16x8*)&B1[(size_t)(j * 16 + fr) * 1536 + 768 + kc];
                acc[j] = __builtin_amdgcn_mfma_f32_16x16x32_bf16(a, b, acc[j], 0, 0, 0);
            }
        }
    }

    // ---- epilogue: +bias, store bf16. C/D: row=(lane>>4)*4+r, col=lane&15 ----
    const int em = (lane >> 4) * 4, en = lane & 15;
#pragma unroll
    for (int j = 0; j < 6; j++) {
        int dcol = j * 16 + en;
        float bias = fb[dcol];
#pragma unroll
        for (int r = 0; r < 4; r++)
            fbuf[(size_t)(mrow + em + r) * 96 + dcol] = f2b(acc[j][r] + bias);
    }
}

// ============================================================
// gemm_o: out1(32768 x 768) = fbuf(32768 x 96 bf16) @ Weff^T(768 x 96 bf16) + b_out
// NO LDS, NO BARRIERS: block = one 16-row strip; wave w covers N-chunk
// [w*192, w*192+192) = 12 j-tiles, K=96 fully unrolled (3 sub-k).
// fbuf strip (3 KB) L1-broadcast to all 4 waves; Weff (147 KB) L2-hot.
// Grid 2048 x 256.
// ============================================================
__global__ __launch_bounds__(256) void gemm_o(const u16* __restrict__ fbuf,
                                              const u16* __restrict__ Weff,
                                              const float* __restrict__ bout,
                                              float* __restrict__ out1) {
    const int tid = threadIdx.x;
    const int lane = tid & 63, wave = tid >> 6;
    const int fr = lane & 15, fk = (lane >> 4) * 8;
    const int m0 = blockIdx.x * 16;
    const int nbase = wave * 192;
    const u16* __restrict__ arow = fbuf + (size_t)(m0 + fr) * 96;

    f32x4 acc[12] = {};
#pragma unroll
    for (int s = 0; s < 3; s++) {
        bf16x8 a = *(const bf16x8*)&arow[s * 32 + fk];
#pragma unroll
        for (int j = 0; j < 12; j++) {
            bf16x8 b = *(const bf16x8*)&Weff[(size_t)(nbase + j * 16 + fr) * 96 + s * 32 + fk];
            acc[j] = __builtin_amdgcn_mfma_f32_16x16x32_bf16(a, b, acc[j], 0, 0, 0);
        }
    }

    const int em = (lane >> 4) * 4, en = lane & 15;
#pragma unroll
    for (int j = 0; j < 12; j++) {
        int col = nbase + j * 16 + en;
        float bias = bout[col];
#pragma unroll
        for (int r = 0; r < 4; r++)
            __builtin_nontemporal_store(acc[j][r] + bias,
                                        &out1[(size_t)(m0 + em + r) * 768 + col]);
    }
}

// ============================================================
extern "C" void kernel_launch(void* const* d_in, const int* in_sizes, int n_in,
                              void* d_out, int out_size, void* d_ws, size_t ws_size,
                              hipStream_t stream) {
    const float* x_rgb       = (const float*)d_in[0];
    const float* x_depth     = (const float*)d_in[1];
    const float* W_qkv_rgb   = (const float*)d_in[2];
    const float* b_qkv_rgb   = (const float*)d_in[3];
    const float* W_qkv_depth = (const float*)d_in[4];
    const float* b_qkv_depth = (const float*)d_in[5];
    const float* W_out       = (const float*)d_in[6];
    const float* b_out       = (const float*)d_in[7];
    const float* aw          = (const float*)d_in[8];

    float* out0 = (float*)d_out;                      // x_rgb passthrough
    float* out1 = out0 + (size_t)M_TOT * 768;         // x_fusion

    char* w = (char*)d_ws;
    u16*   B1   = (u16*)w;                              // 96*1536*2   = 294912
    float* fb   = (float*)(w + 294912);                 // 96*4 -> pad to +512
    u16*   Weff = (u16*)(w + 294912 + 512);             // 768*96*2    = 147456
    u16*   fbuf = (u16*)(w + 294912 + 512 + 147456);    // 32768*96*2  = 6291456

    prep_b1<<<576, 256, 0, stream>>>(W_qkv_rgb, W_qkv_depth, b_qkv_rgb, b_qkv_depth,
                                     aw, B1, fb);
    prep_weff<<<288, 256, 0, stream>>>(W_out, Weff);
    gemm_f<<<512, 256, 0, stream>>>(x_rgb, x_depth, B1, fb, out0, fbuf);
    gemm_o<<<2048, 256, 0, stream>>>(fbuf, Weff, b_out, out1);
}